// Round 6
// baseline (208.487 us; speedup 1.0000x reference)
//
#include <hip/hip_runtime.h>
#include <hip/hip_bf16.h>
#include <stdint.h>

// ---------------------------------------------------------------------------
// TensorDense (tensor-train layer):
//   out[n, abc] = relu( sum_{xyz} x[n, xyz] * W[xyz, abc] + bias[abc] )
//   W[xyz, abc] = sum_{p,q} c1[x,a,p] c2[y,b,p,q] c3[z,c,q]
//
// k_prep : unchanged from R5 (PASS, absmax 0.0078).
// k_gemm : NEW 8-phase-style schedule (T3+T4+T5):
//   BM=256 BN=128 BK=64, 512 thr (8 waves, 4Mx2N, wave tile 64x64),
//   TRIPLE-buffered LDS (144 KB), counted vmcnt(6) never drained in loop,
//   raw s_barrier (no __syncthreads / no vmcnt(0) drain), setprio around
//   MFMA clusters, R5-verified XOR involution swizzle on both sides.
//   Race-freedom: iter i stages tile i+2 into buf[(i+2)%3] whose last
//   reads (tile i-1) completed before iter i's entry barrier.
// ---------------------------------------------------------------------------

typedef short bf16x8 __attribute__((ext_vector_type(8)));  // 8 bf16 = 4 VGPR
typedef float f32x4  __attribute__((ext_vector_type(4)));

#define MB 2048      // batch
#define KD 4096      // input features  (x*256 + y*16 + z)
#define ND 4096      // output features (a*256 + b*16 + c)
#define NT_K 64      // KD / 64 K-tiles

__device__ __forceinline__ unsigned short f32_bf16(float f) {
  union { float f; uint32_t u; } v; v.f = f;
  return (unsigned short)((v.u + 0x7fffu + ((v.u >> 16) & 1u)) >> 16);  // RNE
}
__device__ __forceinline__ float bf2f(unsigned short u) {
  union { uint32_t i; float f; } v; v.i = ((uint32_t)u) << 16; return v.f;
}

// ---------------------------------------------------------------------------
// K0: fused prep (UNCHANGED from R5 PASS).
__global__ __launch_bounds__(256) void k_prep(const float* __restrict__ x,
                                              const float* __restrict__ c1,
                                              const float* __restrict__ c2,
                                              const float* __restrict__ c3,
                                              unsigned short* __restrict__ xb,
                                              unsigned short* __restrict__ Wt) {
  __shared__ unsigned short sh[17472];   // 34944 B
  int bid = blockIdx.x;
  int t = threadIdx.x;

  if (bid < 4096) {            // ---- x fp32 -> bf16, 8 elems/thread ----
    int i = bid * 256 + t;
    const float4* x4 = (const float4*)x;
    float4 a = x4[2*i];
    float4 b = x4[2*i+1];
    ushort4 lo, hi;
    lo.x = f32_bf16(a.x); lo.y = f32_bf16(a.y); lo.z = f32_bf16(a.z); lo.w = f32_bf16(a.w);
    hi.x = f32_bf16(b.x); hi.y = f32_bf16(b.y); hi.z = f32_bf16(b.z); hi.w = f32_bf16(b.w);
    ushort4* o = (ushort4*)xb;
    o[2*i]   = lo;
    o[2*i+1] = hi;
    return;
  }

  // ---- weights block: one (a,b) pair ----
  int ab = bid - 4096;
  int a = ab >> 4, b = ab & 15;
  unsigned short* c2s = sh;                       // [16][1028] shorts
  float* c1s = (float*)(sh + 16448);              // [16][32]

  #pragma unroll
  for (int y = 0; y < 16; ++y) {
    float4 v = *(const float4*)(c2 + (size_t)(y*16 + b)*1024 + t*4);
    ushort4 s;
    s.x = f32_bf16(v.x); s.y = f32_bf16(v.y); s.z = f32_bf16(v.z); s.w = f32_bf16(v.w);
    *(ushort4*)(c2s + y*1028 + t*4) = s;
  }
  c1s[t]       = c1[((t>>5)*16 + a)*32 + (t&31)];
  c1s[t+256]   = c1[(((t>>5)+8)*16 + a)*32 + (t&31)];
  __syncthreads();

  int xx = t >> 4, yy = t & 15;
  const float* c1r = c1s + xx*32;
  const unsigned short* c2r = c2s + yy*1028;
  float acc[32];
  #pragma unroll
  for (int q = 0; q < 32; ++q) acc[q] = 0.f;
  #pragma unroll 8
  for (int p = 0; p < 32; ++p) {
    float w = c1r[p];
    #pragma unroll
    for (int j = 0; j < 8; ++j) {
      ushort4 v = *(const ushort4*)(c2r + p*32 + j*4);
      acc[4*j+0] = fmaf(w, bf2f(v.x), acc[4*j+0]);
      acc[4*j+1] = fmaf(w, bf2f(v.y), acc[4*j+1]);
      acc[4*j+2] = fmaf(w, bf2f(v.z), acc[4*j+2]);
      acc[4*j+3] = fmaf(w, bf2f(v.w), acc[4*j+3]);
    }
  }
  __syncthreads();

  unsigned short* T2s  = sh;          // [256][32] shorts
  unsigned short* c3ps = sh + 8192;   // [256][32] shorts

  #pragma unroll
  for (int j = 0; j < 8; ++j) {
    ushort4 s;
    s.x = f32_bf16(acc[4*j+0]); s.y = f32_bf16(acc[4*j+1]);
    s.z = f32_bf16(acc[4*j+2]); s.w = f32_bf16(acc[4*j+3]);
    *(ushort4*)(T2s + t*32 + j*4) = s;
  }
  #pragma unroll
  for (int r = 0; r < 8; ++r) {
    int i4 = t*8 + r;
    float4 v = *(const float4*)(c3 + (size_t)i4*4);
    int e = i4*4;
    int q = e & 31, zc = e >> 5;
    int z = zc >> 4, c = zc & 15;
    ushort4 s;
    s.x = f32_bf16(v.x); s.y = f32_bf16(v.y); s.z = f32_bf16(v.z); s.w = f32_bf16(v.w);
    *(ushort4*)(c3ps + (c*16 + z)*32 + q) = s;
  }
  __syncthreads();

  int wid = t >> 6, lane = t & 63, l15 = lane & 15, lg = lane >> 4;
  bf16x8 bfv[16];
  #pragma unroll
  for (int nt = 0; nt < 16; ++nt)
    bfv[nt] = *(const bf16x8*)(c3ps + (nt*16 + l15)*32 + lg*8);
  #pragma unroll
  for (int mi = 0; mi < 4; ++mi) {
    int mtile = wid*4 + mi;
    bf16x8 af = *(const bf16x8*)(T2s + (mtile*16 + l15)*32 + lg*8);
    #pragma unroll
    for (int nt = 0; nt < 16; ++nt) {
      f32x4 d = {0.f, 0.f, 0.f, 0.f};
      d = __builtin_amdgcn_mfma_f32_16x16x32_bf16(af, bfv[nt], d, 0, 0, 0);
      size_t jrow = (size_t)(ab*16 + nt) * ND;
      #pragma unroll
      for (int i = 0; i < 4; ++i) {
        int xy = mtile*16 + lg*4 + i;
        Wt[jrow + xy*16 + l15] = f32_bf16(d[i]);
      }
    }
  }
}

// ---------------------------------------------------------------------------
// K1: deep-pipelined GEMM.
__device__ __forceinline__ void gload_lds16(const unsigned short* g, unsigned short* l) {
  __builtin_amdgcn_global_load_lds(
      (const __attribute__((address_space(1))) void*)g,
      (__attribute__((address_space(3))) void*)l, 16, 0, 0);
}

// phase loads: 2 A-frags (rows H*2..H*2+1 of wave's 4) + (H==0) all 4 B-frags
template<int H, int KK>
__device__ __forceinline__ void phase_loads(const unsigned short* Ac, const unsigned short* Bc,
                                            int wr, int wc, int l15, int lg, int xr,
                                            bf16x8& a0, bf16x8& a1, bf16x8 (&bF)[2][4]) {
  const int pc8 = ((KK*4 + lg) ^ xr) * 8;   // physical col16 * 8 shorts
  a0 = *(const bf16x8*)(Ac + (wr*64 + (H*2+0)*16 + l15)*64 + pc8);
  a1 = *(const bf16x8*)(Ac + (wr*64 + (H*2+1)*16 + l15)*64 + pc8);
  if (H == 0) {
    #pragma unroll
    for (int n = 0; n < 4; ++n)
      bF[KK][n] = *(const bf16x8*)(Bc + (wc*64 + n*16 + l15)*64 + pc8);
  }
}

template<int H, int KK>
__device__ __forceinline__ void phase_fma(const bf16x8& a0, const bf16x8& a1,
                                          bf16x8 (&bF)[2][4], f32x4 (&acc)[4][4]) {
  #pragma unroll
  for (int n = 0; n < 4; ++n) {
    acc[H*2+0][n] = __builtin_amdgcn_mfma_f32_16x16x32_bf16(a0, bF[KK][n], acc[H*2+0][n], 0, 0, 0);
    acc[H*2+1][n] = __builtin_amdgcn_mfma_f32_16x16x32_bf16(a1, bF[KK][n], acc[H*2+1][n], 0, 0, 0);
  }
}

__global__ __launch_bounds__(512, 1) void k_gemm(const unsigned short* __restrict__ A,
                                                 const unsigned short* __restrict__ Bw,
                                                 const float* __restrict__ bias,
                                                 float* __restrict__ C) {
  __shared__ unsigned short As[3*256*64];   // 96 KB, 3 K-tile buffers
  __shared__ unsigned short Bs[3*128*64];   // 48 KB
  const int t = threadIdx.x;
  const int wid = t >> 6, lane = t & 63;
  const int l15 = lane & 15, lg = lane >> 4;
  const int m0 = blockIdx.y * 256;
  const int n0 = blockIdx.x * 128;
  const int wr = wid >> 1, wc = wid & 1;    // 4M x 2N waves, wave tile 64x64
  const int xr = l15 & 7;

  // staging (R5-verified involution): inst s writes LDS linear t*16B =
  // row s*64+(t>>3), physical col16 t&7; source col16 = (t&7)^(row&7).
  const int scol = (((t & 7) ^ ((t >> 3) & 7)) * 8);
  const int t8 = t * 8;
  const unsigned short* Ag = A  + (size_t)(m0 + (t >> 3))*KD + scol;
  const unsigned short* Bg = Bw + (size_t)(n0 + (t >> 3))*KD + scol;

#define STG_A(tk, buf, s) gload_lds16(Ag + (size_t)(s)*64*KD + (tk)*64, \
                                      As + (buf)*16384 + (s)*4096 + t8)
#define STG_B(tk, buf, s) gload_lds16(Bg + (size_t)(s)*64*KD + (tk)*64, \
                                      Bs + (buf)*8192  + (s)*4096 + t8)

  f32x4 acc[4][4];
  #pragma unroll
  for (int m = 0; m < 4; ++m)
    #pragma unroll
    for (int n = 0; n < 4; ++n)
      acc[m][n] = (f32x4){0.f, 0.f, 0.f, 0.f};
  bf16x8 bF[2][4];

  // prologue: tile 0 -> buf0 (6 insts), tile 1 -> buf1 (6 insts);
  // vmcnt(6) => tile 0 landed; tile 1 stays in flight.
  STG_A(0,0,0); STG_A(0,0,1); STG_A(0,0,2); STG_A(0,0,3); STG_B(0,0,0); STG_B(0,0,1);
  STG_A(1,1,0); STG_A(1,1,1); STG_A(1,1,2); STG_A(1,1,3); STG_B(1,1,0); STG_B(1,1,1);
  asm volatile("s_waitcnt vmcnt(6)" ::: "memory");
  __builtin_amdgcn_s_barrier();

  int cur = 0, stg = 2;
  for (int i = 0; i < NT_K; ++i) {
    const unsigned short* Ac = As + cur*16384;
    const unsigned short* Bc = Bs + cur*8192;
    const int  tk2 = i + 2;
    const bool do_stage = (i < NT_K - 2);
    bf16x8 a0, a1;

    // ---- phase 1: (h=0, kk=0) + stage A insts 0,1 of tile i+2 ----
    phase_loads<0,0>(Ac, Bc, wr, wc, l15, lg, xr, a0, a1, bF);
    if (do_stage) { STG_A(tk2, stg, 0); STG_A(tk2, stg, 1); }
    __builtin_amdgcn_s_barrier();
    asm volatile("s_waitcnt lgkmcnt(0)" ::: "memory");
    __builtin_amdgcn_sched_barrier(0);
    __builtin_amdgcn_s_setprio(1);
    phase_fma<0,0>(a0, a1, bF, acc);
    __builtin_amdgcn_s_setprio(0);
    __builtin_amdgcn_s_barrier();

    // ---- phase 2: (h=1, kk=0) + stage A insts 2,3 ----
    phase_loads<1,0>(Ac, Bc, wr, wc, l15, lg, xr, a0, a1, bF);
    if (do_stage) { STG_A(tk2, stg, 2); STG_A(tk2, stg, 3); }
    __builtin_amdgcn_s_barrier();
    asm volatile("s_waitcnt lgkmcnt(0)" ::: "memory");
    __builtin_amdgcn_sched_barrier(0);
    __builtin_amdgcn_s_setprio(1);
    phase_fma<1,0>(a0, a1, bF, acc);
    __builtin_amdgcn_s_setprio(0);
    __builtin_amdgcn_s_barrier();

    // ---- phase 3: (h=0, kk=1) + stage B insts 0,1 ----
    phase_loads<0,1>(Ac, Bc, wr, wc, l15, lg, xr, a0, a1, bF);
    if (do_stage) { STG_B(tk2, stg, 0); STG_B(tk2, stg, 1); }
    __builtin_amdgcn_s_barrier();
    asm volatile("s_waitcnt lgkmcnt(0)" ::: "memory");
    __builtin_amdgcn_sched_barrier(0);
    __builtin_amdgcn_s_setprio(1);
    phase_fma<0,1>(a0, a1, bF, acc);
    __builtin_amdgcn_s_setprio(0);
    __builtin_amdgcn_s_barrier();

    // ---- phase 4: (h=1, kk=1), no staging ----
    phase_loads<1,1>(Ac, Bc, wr, wc, l15, lg, xr, a0, a1, bF);
    __builtin_amdgcn_s_barrier();
    asm volatile("s_waitcnt lgkmcnt(0)" ::: "memory");
    __builtin_amdgcn_sched_barrier(0);
    __builtin_amdgcn_s_setprio(1);
    phase_fma<1,1>(a0, a1, bF, acc);
    __builtin_amdgcn_s_setprio(0);

    // iteration gate: tile i+1 must be landed; tile i+2 (6 insts) stays
    // in flight -> vmcnt(6), NEVER 0 in steady state (T4).
    if (i < NT_K - 2)       { asm volatile("s_waitcnt vmcnt(6)" ::: "memory"); }
    else if (i == NT_K - 2) { asm volatile("s_waitcnt vmcnt(0)" ::: "memory"); }
    __builtin_amdgcn_s_barrier();

    cur = (cur == 2) ? 0 : cur + 1;
    stg = (stg == 2) ? 0 : stg + 1;
  }

  // epilogue: bias + relu, fp32 stores (registers only; no barrier needed)
  #pragma unroll
  for (int m = 0; m < 4; ++m) {
    int gr = m0 + wr*64 + m*16 + lg*4;
    #pragma unroll
    for (int n = 0; n < 4; ++n) {
      int gc = n0 + wc*64 + n*16 + l15;
      float bv = bias[gc];
      #pragma unroll
      for (int i = 0; i < 4; ++i) {
        float v = acc[m][n][i] + bv;
        C[(size_t)(gr + i)*ND + gc] = v > 0.f ? v : 0.f;
      }
    }
  }
#undef STG_A
#undef STG_B
}

// ---------------------------------------------------------------------------
extern "C" void kernel_launch(void* const* d_in, const int* in_sizes, int n_in,
                              void* d_out, int out_size, void* d_ws, size_t ws_size,
                              hipStream_t stream) {
  (void)in_sizes; (void)n_in; (void)out_size; (void)ws_size;
  const float* x    = (const float*)d_in[0];   // [2048][4096]
  const float* c1   = (const float*)d_in[1];   // [16][16][32]
  const float* c2   = (const float*)d_in[2];   // [16][16][32][32]
  const float* c3   = (const float*)d_in[3];   // [16][16][32]
  const float* bias = (const float*)d_in[4];   // [4096]
  float* out = (float*)d_out;                  // [2048][4096]

  uint8_t* ws = (uint8_t*)d_ws;
  unsigned short* xb = (unsigned short*)(ws);              // 16 MB
  unsigned short* Wt = (unsigned short*)(ws + 16777216);   // 32 MB

  k_prep<<<4096 + 256, 256, 0, stream>>>(x, c1, c2, c3, xb, Wt);
  k_gemm<<<dim3(ND/128, MB/256), 512, 0, stream>>>(xb, Wt, bias, out);
}

// Round 7
// 171.690 us; speedup vs baseline: 1.2143x; 1.2143x over previous
//
#include <hip/hip_runtime.h>
#include <hip/hip_bf16.h>
#include <stdint.h>

// ---------------------------------------------------------------------------
// TensorDense (tensor-train layer):
//   out[n, abc] = relu( sum_{xyz} x[n, xyz] * W[xyz, abc] + bias[abc] )
//   W[xyz, abc] = sum_{p,q} c1[x,a,p] c2[y,b,p,q] c3[z,c,q]
//
// 3 dispatches (k_prep split for profile visibility):
//   k_conv : x fp32 -> bf16.
//   k_wt   : build Wt = W^T bf16 [j=abc][k=xyz], one (a,b) per block.
//   k_gemm : deep-pipelined MFMA GEMM, R7 structure:
//     BM=128 BN=256 BK=64, 512 thr (8 waves, 2Mx4N, wave tile 64x64),
//     grid (16,16)=256 blocks = 1/CU. Triple-buffered LDS (144 KB).
//     Per K-tile: 2 phases x {8 ds_read_b128 + 3 stage -> barrier ->
//     lgkmcnt(0) -> setprio(1) 16 MFMA setprio(0) -> [vmcnt(6)] barrier}
//     = 4 barriers / 64 MFMA (m201 ratio; R6 had 9/32 -> regressed).
//     Counted vmcnt never drains to 0 in steady state (T4).
// ---------------------------------------------------------------------------

typedef short bf16x8 __attribute__((ext_vector_type(8)));  // 8 bf16 = 4 VGPR
typedef float f32x4  __attribute__((ext_vector_type(4)));

#define MB 2048      // batch
#define KD 4096      // input features  (x*256 + y*16 + z)
#define ND 4096      // output features (a*256 + b*16 + c)
#define NT_K 64      // KD / 64 K-tiles

__device__ __forceinline__ unsigned short f32_bf16(float f) {
  union { float f; uint32_t u; } v; v.f = f;
  return (unsigned short)((v.u + 0x7fffu + ((v.u >> 16) & 1u)) >> 16);  // RNE
}
__device__ __forceinline__ float bf2f(unsigned short u) {
  union { uint32_t i; float f; } v; v.i = ((uint32_t)u) << 16; return v.f;
}

// --- K0: x fp32 -> bf16 ----------------------------------------------------
__global__ void k_conv(const float* __restrict__ x, unsigned short* __restrict__ xb) {
  int i = blockIdx.x * 256 + threadIdx.x;
  const float4* x4 = (const float4*)x;
  float4 a = x4[2*i];
  float4 b = x4[2*i+1];
  ushort4 lo, hi;
  lo.x = f32_bf16(a.x); lo.y = f32_bf16(a.y); lo.z = f32_bf16(a.z); lo.w = f32_bf16(a.w);
  hi.x = f32_bf16(b.x); hi.y = f32_bf16(b.y); hi.z = f32_bf16(b.z); hi.w = f32_bf16(b.w);
  ushort4* o = (ushort4*)xb;
  o[2*i]   = lo;
  o[2*i+1] = hi;
}

// --- K1: weights build (R5-verified logic, standalone) ---------------------
__global__ __launch_bounds__(256) void k_wt(const float* __restrict__ c1,
                                            const float* __restrict__ c2,
                                            const float* __restrict__ c3,
                                            unsigned short* __restrict__ Wt) {
  __shared__ unsigned short sh[17472];   // 34944 B
  int ab = blockIdx.x;
  int t = threadIdx.x;
  int a = ab >> 4, b = ab & 15;
  unsigned short* c2s = sh;                       // [16][1028] shorts
  float* c1s = (float*)(sh + 16448);              // [16][32]

  #pragma unroll
  for (int y = 0; y < 16; ++y) {
    float4 v = *(const float4*)(c2 + (size_t)(y*16 + b)*1024 + t*4);
    ushort4 s;
    s.x = f32_bf16(v.x); s.y = f32_bf16(v.y); s.z = f32_bf16(v.z); s.w = f32_bf16(v.w);
    *(ushort4*)(c2s + y*1028 + t*4) = s;
  }
  c1s[t]       = c1[((t>>5)*16 + a)*32 + (t&31)];
  c1s[t+256]   = c1[(((t>>5)+8)*16 + a)*32 + (t&31)];
  __syncthreads();

  int xx = t >> 4, yy = t & 15;
  const float* c1r = c1s + xx*32;
  const unsigned short* c2r = c2s + yy*1028;
  float acc[32];
  #pragma unroll
  for (int q = 0; q < 32; ++q) acc[q] = 0.f;
  #pragma unroll 8
  for (int p = 0; p < 32; ++p) {
    float w = c1r[p];
    #pragma unroll
    for (int j = 0; j < 8; ++j) {
      ushort4 v = *(const ushort4*)(c2r + p*32 + j*4);
      acc[4*j+0] = fmaf(w, bf2f(v.x), acc[4*j+0]);
      acc[4*j+1] = fmaf(w, bf2f(v.y), acc[4*j+1]);
      acc[4*j+2] = fmaf(w, bf2f(v.z), acc[4*j+2]);
      acc[4*j+3] = fmaf(w, bf2f(v.w), acc[4*j+3]);
    }
  }
  __syncthreads();

  unsigned short* T2s  = sh;          // [256][32] shorts
  unsigned short* c3ps = sh + 8192;   // [256][32] shorts

  #pragma unroll
  for (int j = 0; j < 8; ++j) {
    ushort4 s;
    s.x = f32_bf16(acc[4*j+0]); s.y = f32_bf16(acc[4*j+1]);
    s.z = f32_bf16(acc[4*j+2]); s.w = f32_bf16(acc[4*j+3]);
    *(ushort4*)(T2s + t*32 + j*4) = s;
  }
  #pragma unroll
  for (int r = 0; r < 8; ++r) {
    int i4 = t*8 + r;
    float4 v = *(const float4*)(c3 + (size_t)i4*4);
    int e = i4*4;
    int q = e & 31, zc = e >> 5;
    int z = zc >> 4, c = zc & 15;
    ushort4 s;
    s.x = f32_bf16(v.x); s.y = f32_bf16(v.y); s.z = f32_bf16(v.z); s.w = f32_bf16(v.w);
    *(ushort4*)(c3ps + (c*16 + z)*32 + q) = s;
  }
  __syncthreads();

  int wid = t >> 6, lane = t & 63, l15 = lane & 15, lg = lane >> 4;
  bf16x8 bfv[16];
  #pragma unroll
  for (int nt = 0; nt < 16; ++nt)
    bfv[nt] = *(const bf16x8*)(c3ps + (nt*16 + l15)*32 + lg*8);
  #pragma unroll
  for (int mi = 0; mi < 4; ++mi) {
    int mtile = wid*4 + mi;
    bf16x8 af = *(const bf16x8*)(T2s + (mtile*16 + l15)*32 + lg*8);
    #pragma unroll
    for (int nt = 0; nt < 16; ++nt) {
      f32x4 d = {0.f, 0.f, 0.f, 0.f};
      d = __builtin_amdgcn_mfma_f32_16x16x32_bf16(af, bfv[nt], d, 0, 0, 0);
      size_t jrow = (size_t)(ab*16 + nt) * ND;
      #pragma unroll
      for (int i = 0; i < 4; ++i) {
        int xy = mtile*16 + lg*4 + i;
        Wt[jrow + xy*16 + l15] = f32_bf16(d[i]);
      }
    }
  }
}

// ---------------------------------------------------------------------------
// K2: deep-pipelined GEMM out[n][j] = relu(sum_k xb[n][k]*Wt[j][k] + bias[j])
__device__ __forceinline__ void gload_lds16(const unsigned short* g, unsigned short* l) {
  __builtin_amdgcn_global_load_lds(
      (const __attribute__((address_space(1))) void*)g,
      (__attribute__((address_space(3))) void*)l, 16, 0, 0);
}

__global__ __launch_bounds__(512, 1) void k_gemm(const unsigned short* __restrict__ A,
                                                 const unsigned short* __restrict__ Bw,
                                                 const float* __restrict__ bias,
                                                 float* __restrict__ C) {
  __shared__ unsigned short As[3*128*64];   // 48 KB, 3 K-tile buffers (BM=128)
  __shared__ unsigned short Bs[3*256*64];   // 96 KB                  (BN=256)
  const int t = threadIdx.x;
  const int wid = t >> 6, lane = t & 63;
  const int l15 = lane & 15, lg = lane >> 4;
  const int m0 = blockIdx.y * 128;          // batch rows
  const int n0 = blockIdx.x * 256;          // output cols
  const int wr = wid >> 2, wc = wid & 3;    // 2M x 4N waves, wave tile 64x64
  const int xr = l15 & 7;

  // staging (R5-verified involution): inst s writes LDS linear t*16B =
  // row s*64+(t>>3), physical col16 t&7; source col16 = (t&7)^(row&7).
  const int scol = (((t & 7) ^ ((t >> 3) & 7)) * 8);
  const int t8 = t * 8;
  const unsigned short* Ag = A  + (size_t)(m0 + (t >> 3))*KD + scol;
  const unsigned short* Bg = Bw + (size_t)(n0 + (t >> 3))*KD + scol;

  // A tile: 128x64 shorts = 8192 shorts/tile, 2 insts; B: 16384 shorts, 4.
#define STG_A(tk, buf, s) gload_lds16(Ag + (size_t)(s)*64*KD + (tk)*64, \
                                      As + (buf)*8192  + (s)*4096 + t8)
#define STG_B(tk, buf, s) gload_lds16(Bg + (size_t)(s)*64*KD + (tk)*64, \
                                      Bs + (buf)*16384 + (s)*4096 + t8)

  f32x4 acc[4][4];
  #pragma unroll
  for (int m = 0; m < 4; ++m)
    #pragma unroll
    for (int n = 0; n < 4; ++n)
      acc[m][n] = (f32x4){0.f, 0.f, 0.f, 0.f};

  // prologue: tile 0 -> buf0, tile 1 -> buf1 (6 insts each);
  // vmcnt(6) => tile 0 landed, tile 1 in flight.
  STG_A(0,0,0); STG_A(0,0,1); STG_B(0,0,0); STG_B(0,0,1); STG_B(0,0,2); STG_B(0,0,3);
  STG_A(1,1,0); STG_A(1,1,1); STG_B(1,1,0); STG_B(1,1,1); STG_B(1,1,2); STG_B(1,1,3);
  asm volatile("s_waitcnt vmcnt(6)" ::: "memory");
  __builtin_amdgcn_s_barrier();

  int cur = 0, stg = 2;
  for (int i = 0; i < NT_K; ++i) {
    const unsigned short* Ac = As + cur*8192;
    const unsigned short* Bc = Bs + cur*16384;
    const int  tk2 = i + 2;
    const bool do_stage = (i < NT_K - 2);
    bf16x8 aF[4], bF[4];

    // ===== phase 1 (kk=0): 8 ds_read + 3 stage -> 16 MFMA =====
    {
      const int pc8 = ((0*4 + lg) ^ xr) * 8;
      #pragma unroll
      for (int m = 0; m < 4; ++m)
        aF[m] = *(const bf16x8*)(Ac + (wr*64 + m*16 + l15)*64 + pc8);
      #pragma unroll
      for (int n = 0; n < 4; ++n)
        bF[n] = *(const bf16x8*)(Bc + (wc*64 + n*16 + l15)*64 + pc8);
    }
    if (do_stage) { STG_A(tk2, stg, 0); STG_A(tk2, stg, 1); STG_B(tk2, stg, 0); }
    __builtin_amdgcn_s_barrier();
    asm volatile("s_waitcnt lgkmcnt(0)" ::: "memory");
    __builtin_amdgcn_sched_barrier(0);
    __builtin_amdgcn_s_setprio(1);
    #pragma unroll
    for (int m = 0; m < 4; ++m)
      #pragma unroll
      for (int n = 0; n < 4; ++n)
        acc[m][n] = __builtin_amdgcn_mfma_f32_16x16x32_bf16(aF[m], bF[n], acc[m][n], 0, 0, 0);
    __builtin_amdgcn_s_setprio(0);
    __builtin_amdgcn_s_barrier();

    // ===== phase 2 (kk=1): 8 ds_read + 3 stage -> 16 MFMA =====
    {
      const int pc8 = ((1*4 + lg) ^ xr) * 8;
      #pragma unroll
      for (int m = 0; m < 4; ++m)
        aF[m] = *(const bf16x8*)(Ac + (wr*64 + m*16 + l15)*64 + pc8);
      #pragma unroll
      for (int n = 0; n < 4; ++n)
        bF[n] = *(const bf16x8*)(Bc + (wc*64 + n*16 + l15)*64 + pc8);
    }
    if (do_stage) { STG_B(tk2, stg, 1); STG_B(tk2, stg, 2); STG_B(tk2, stg, 3); }
    __builtin_amdgcn_s_barrier();
    asm volatile("s_waitcnt lgkmcnt(0)" ::: "memory");
    __builtin_amdgcn_sched_barrier(0);
    __builtin_amdgcn_s_setprio(1);
    #pragma unroll
    for (int m = 0; m < 4; ++m)
      #pragma unroll
      for (int n = 0; n < 4; ++n)
        acc[m][n] = __builtin_amdgcn_mfma_f32_16x16x32_bf16(aF[m], bF[n], acc[m][n], 0, 0, 0);
    __builtin_amdgcn_s_setprio(0);

    // gate fused into phase-2 closing barrier: tile i+1 landed, tile i+2
    // (6 insts) stays in flight -> vmcnt(6), never 0 in steady state.
    if (i < NT_K - 2)       { asm volatile("s_waitcnt vmcnt(6)" ::: "memory"); }
    else if (i == NT_K - 2) { asm volatile("s_waitcnt vmcnt(0)" ::: "memory"); }
    __builtin_amdgcn_s_barrier();

    cur = (cur == 2) ? 0 : cur + 1;
    stg = (stg == 2) ? 0 : stg + 1;
  }

  // epilogue: bias + relu, fp32 stores (registers only)
  #pragma unroll
  for (int m = 0; m < 4; ++m) {
    int gr = m0 + wr*64 + m*16 + lg*4;
    #pragma unroll
    for (int n = 0; n < 4; ++n) {
      int gc = n0 + wc*64 + n*16 + l15;
      float bv = bias[gc];
      #pragma unroll
      for (int i = 0; i < 4; ++i) {
        float v = acc[m][n][i] + bv;
        C[(size_t)(gr + i)*ND + gc] = v > 0.f ? v : 0.f;
      }
    }
  }
#undef STG_A
#undef STG_B
}

// ---------------------------------------------------------------------------
extern "C" void kernel_launch(void* const* d_in, const int* in_sizes, int n_in,
                              void* d_out, int out_size, void* d_ws, size_t ws_size,
                              hipStream_t stream) {
  (void)in_sizes; (void)n_in; (void)out_size; (void)ws_size;
  const float* x    = (const float*)d_in[0];   // [2048][4096]
  const float* c1   = (const float*)d_in[1];   // [16][16][32]
  const float* c2   = (const float*)d_in[2];   // [16][16][32][32]
  const float* c3   = (const float*)d_in[3];   // [16][16][32]
  const float* bias = (const float*)d_in[4];   // [4096]
  float* out = (float*)d_out;                  // [2048][4096]

  uint8_t* ws = (uint8_t*)d_ws;
  unsigned short* xb = (unsigned short*)(ws);              // 16 MB
  unsigned short* Wt = (unsigned short*)(ws + 16777216);   // 32 MB

  k_conv<<<4096, 256, 0, stream>>>(x, xb);
  k_wt  <<<256,  256, 0, stream>>>(c1, c2, c3, Wt);
  k_gemm<<<dim3(ND/256, MB/128), 512, 0, stream>>>(xb, Wt, bias, out);
}

// Round 8
// 163.458 us; speedup vs baseline: 1.2755x; 1.0504x over previous
//
#include <hip/hip_runtime.h>
#include <hip/hip_bf16.h>
#include <stdint.h>

// ---------------------------------------------------------------------------
// TensorDense (tensor-train layer):
//   out[n, abc] = relu( sum_{xyz} x[n, xyz] * W[xyz, abc] + bias[abc] )
//   W[xyz, abc] = sum_{p,q} c1[x,a,p] c2[y,b,p,q] c3[z,c,q]
//
// 3 dispatches:
//   k_conv : x fp32 -> bf16.
//   k_wt   : build Wt = W^T bf16 [j=abc][k=xyz], one (a,b) per block.
//   k_gemm : R8 structure. BM=128 BN=256 BK=64, 512 thr, grid 16x16=256
//     blocks = 1/CU. 8 waves: wave w in 0..3 pairs with w+4; each pair owns
//     a 128x64 output tile (wc = wid&3), pair-split over K (kkw = wid>>2).
//     Per wave per K-tile: 12 ds_read_b128 -> 32 MFMA (reads<=MFMA on SIMD),
//     ONE barrier per K-tile. Triple-buffered LDS, counted vmcnt(6) (T4),
//     setprio around MFMA (T5), R5-verified XOR involution swizzle (T2).
//     Epilogue: pair-merge partials via LDS, bias+relu, store.
// ---------------------------------------------------------------------------

typedef short bf16x8 __attribute__((ext_vector_type(8)));  // 8 bf16 = 4 VGPR
typedef float f32x4  __attribute__((ext_vector_type(4)));

#define MB 2048      // batch
#define KD 4096      // input features  (x*256 + y*16 + z)
#define ND 4096      // output features (a*256 + b*16 + c)
#define NT_K 64      // KD / 64 K-tiles

__device__ __forceinline__ unsigned short f32_bf16(float f) {
  union { float f; uint32_t u; } v; v.f = f;
  return (unsigned short)((v.u + 0x7fffu + ((v.u >> 16) & 1u)) >> 16);  // RNE
}
__device__ __forceinline__ float bf2f(unsigned short u) {
  union { uint32_t i; float f; } v; v.i = ((uint32_t)u) << 16; return v.f;
}

// --- K0: x fp32 -> bf16 ----------------------------------------------------
__global__ void k_conv(const float* __restrict__ x, unsigned short* __restrict__ xb) {
  int i = blockIdx.x * 256 + threadIdx.x;
  const float4* x4 = (const float4*)x;
  float4 a = x4[2*i];
  float4 b = x4[2*i+1];
  ushort4 lo, hi;
  lo.x = f32_bf16(a.x); lo.y = f32_bf16(a.y); lo.z = f32_bf16(a.z); lo.w = f32_bf16(a.w);
  hi.x = f32_bf16(b.x); hi.y = f32_bf16(b.y); hi.z = f32_bf16(b.z); hi.w = f32_bf16(b.w);
  ushort4* o = (ushort4*)xb;
  o[2*i]   = lo;
  o[2*i+1] = hi;
}

// --- K1: weights build (R5-verified logic, standalone) ---------------------
__global__ __launch_bounds__(256) void k_wt(const float* __restrict__ c1,
                                            const float* __restrict__ c2,
                                            const float* __restrict__ c3,
                                            unsigned short* __restrict__ Wt) {
  __shared__ unsigned short sh[17472];   // 34944 B
  int ab = blockIdx.x;
  int t = threadIdx.x;
  int a = ab >> 4, b = ab & 15;
  unsigned short* c2s = sh;                       // [16][1028] shorts
  float* c1s = (float*)(sh + 16448);              // [16][32]

  #pragma unroll
  for (int y = 0; y < 16; ++y) {
    float4 v = *(const float4*)(c2 + (size_t)(y*16 + b)*1024 + t*4);
    ushort4 s;
    s.x = f32_bf16(v.x); s.y = f32_bf16(v.y); s.z = f32_bf16(v.z); s.w = f32_bf16(v.w);
    *(ushort4*)(c2s + y*1028 + t*4) = s;
  }
  c1s[t]       = c1[((t>>5)*16 + a)*32 + (t&31)];
  c1s[t+256]   = c1[(((t>>5)+8)*16 + a)*32 + (t&31)];
  __syncthreads();

  int xx = t >> 4, yy = t & 15;
  const float* c1r = c1s + xx*32;
  const unsigned short* c2r = c2s + yy*1028;
  float acc[32];
  #pragma unroll
  for (int q = 0; q < 32; ++q) acc[q] = 0.f;
  #pragma unroll 8
  for (int p = 0; p < 32; ++p) {
    float w = c1r[p];
    #pragma unroll
    for (int j = 0; j < 8; ++j) {
      ushort4 v = *(const ushort4*)(c2r + p*32 + j*4);
      acc[4*j+0] = fmaf(w, bf2f(v.x), acc[4*j+0]);
      acc[4*j+1] = fmaf(w, bf2f(v.y), acc[4*j+1]);
      acc[4*j+2] = fmaf(w, bf2f(v.z), acc[4*j+2]);
      acc[4*j+3] = fmaf(w, bf2f(v.w), acc[4*j+3]);
    }
  }
  __syncthreads();

  unsigned short* T2s  = sh;          // [256][32] shorts
  unsigned short* c3ps = sh + 8192;   // [256][32] shorts

  #pragma unroll
  for (int j = 0; j < 8; ++j) {
    ushort4 s;
    s.x = f32_bf16(acc[4*j+0]); s.y = f32_bf16(acc[4*j+1]);
    s.z = f32_bf16(acc[4*j+2]); s.w = f32_bf16(acc[4*j+3]);
    *(ushort4*)(T2s + t*32 + j*4) = s;
  }
  #pragma unroll
  for (int r = 0; r < 8; ++r) {
    int i4 = t*8 + r;
    float4 v = *(const float4*)(c3 + (size_t)i4*4);
    int e = i4*4;
    int q = e & 31, zc = e >> 5;
    int z = zc >> 4, c = zc & 15;
    ushort4 s;
    s.x = f32_bf16(v.x); s.y = f32_bf16(v.y); s.z = f32_bf16(v.z); s.w = f32_bf16(v.w);
    *(ushort4*)(c3ps + (c*16 + z)*32 + q) = s;
  }
  __syncthreads();

  int wid = t >> 6, lane = t & 63, l15 = lane & 15, lg = lane >> 4;
  bf16x8 bfv[16];
  #pragma unroll
  for (int nt = 0; nt < 16; ++nt)
    bfv[nt] = *(const bf16x8*)(c3ps + (nt*16 + l15)*32 + lg*8);
  #pragma unroll
  for (int mi = 0; mi < 4; ++mi) {
    int mtile = wid*4 + mi;
    bf16x8 af = *(const bf16x8*)(T2s + (mtile*16 + l15)*32 + lg*8);
    #pragma unroll
    for (int nt = 0; nt < 16; ++nt) {
      f32x4 d = {0.f, 0.f, 0.f, 0.f};
      d = __builtin_amdgcn_mfma_f32_16x16x32_bf16(af, bfv[nt], d, 0, 0, 0);
      size_t jrow = (size_t)(ab*16 + nt) * ND;
      #pragma unroll
      for (int i = 0; i < 4; ++i) {
        int xy = mtile*16 + lg*4 + i;
        Wt[jrow + xy*16 + l15] = f32_bf16(d[i]);
      }
    }
  }
}

// ---------------------------------------------------------------------------
// K2: GEMM out[n][j] = relu(sum_k xb[n][k]*Wt[j][k] + bias[j])
__device__ __forceinline__ void gload_lds16(const unsigned short* g, unsigned short* l) {
  __builtin_amdgcn_global_load_lds(
      (const __attribute__((address_space(1))) void*)g,
      (__attribute__((address_space(3))) void*)l, 16, 0, 0);
}

__global__ __launch_bounds__(512, 1) void k_gemm(const unsigned short* __restrict__ A,
                                                 const unsigned short* __restrict__ Bw,
                                                 const float* __restrict__ bias,
                                                 float* __restrict__ C) {
  __shared__ uint8_t sh[147456];        // 144 KB: As 3x16 KB | Bs 3x32 KB
  unsigned short* As = (unsigned short*)sh;             // 3 x [128][64]
  unsigned short* Bs = (unsigned short*)(sh + 49152);   // 3 x [256][64]
  const int t = threadIdx.x;
  const int wid = t >> 6, lane = t & 63;
  const int l15 = lane & 15, lg = lane >> 4;
  const int m0 = blockIdx.y * 128;          // batch rows
  const int n0 = blockIdx.x * 256;          // output cols
  const int wc  = wid & 3;                  // pair's output col tile (64 wide)
  const int kkw = wid >> 2;                 // K-split half within BK=64
  const int xr = l15 & 7;

  // staging (R5-verified involution): inst s writes LDS linear t*16B =
  // row s*64+(t>>3), physical col16 t&7; source col16 = (t&7)^(row&7).
  const int scol = (((t & 7) ^ ((t >> 3) & 7)) * 8);
  const int t8 = t * 8;
  const unsigned short* Ag = A  + (size_t)(m0 + (t >> 3))*KD + scol;
  const unsigned short* Bg = Bw + (size_t)(n0 + (t >> 3))*KD + scol;

  // A tile 8192 shorts (2 insts), B tile 16384 shorts (4 insts)
#define STG_A(tk, buf, s) gload_lds16(Ag + (size_t)(s)*64*KD + (tk)*64, \
                                      As + (buf)*8192  + (s)*4096 + t8)
#define STG_B(tk, buf, s) gload_lds16(Bg + (size_t)(s)*64*KD + (tk)*64, \
                                      Bs + (buf)*16384 + (s)*4096 + t8)

  f32x4 acc[8][4];
  #pragma unroll
  for (int m = 0; m < 8; ++m)
    #pragma unroll
    for (int n = 0; n < 4; ++n)
      acc[m][n] = (f32x4){0.f, 0.f, 0.f, 0.f};

  // prologue: tile 0 -> buf0, tile 1 -> buf1; vmcnt(6) => tile 0 landed.
  STG_A(0,0,0); STG_A(0,0,1); STG_B(0,0,0); STG_B(0,0,1); STG_B(0,0,2); STG_B(0,0,3);
  STG_A(1,1,0); STG_A(1,1,1); STG_B(1,1,0); STG_B(1,1,1); STG_B(1,1,2); STG_B(1,1,3);
  asm volatile("s_waitcnt vmcnt(6)" ::: "memory");
  __builtin_amdgcn_s_barrier();

  // fragment read column (swizzled): logical col16 = kkw*4+lg
  const int pc8 = ((kkw*4 + lg) ^ xr) * 8;

  int cur = 0, stg = 2;
  for (int i = 0; i < NT_K; ++i) {
    const unsigned short* Ac = As + cur*8192;
    const unsigned short* Bc = Bs + cur*16384;
    bf16x8 aF[8], bF[4];
    #pragma unroll
    for (int m = 0; m < 8; ++m)
      aF[m] = *(const bf16x8*)(Ac + (m*16 + l15)*64 + pc8);
    #pragma unroll
    for (int n = 0; n < 4; ++n)
      bF[n] = *(const bf16x8*)(Bc + (wc*64 + n*16 + l15)*64 + pc8);
    if (i < NT_K - 2) {
      const int tk2 = i + 2;
      STG_A(tk2, stg, 0); STG_A(tk2, stg, 1);
      STG_B(tk2, stg, 0); STG_B(tk2, stg, 1); STG_B(tk2, stg, 2); STG_B(tk2, stg, 3);
    }
    asm volatile("s_waitcnt lgkmcnt(0)" ::: "memory");
    __builtin_amdgcn_sched_barrier(0);
    __builtin_amdgcn_s_setprio(1);
    #pragma unroll
    for (int m = 0; m < 8; ++m)
      #pragma unroll
      for (int n = 0; n < 4; ++n)
        acc[m][n] = __builtin_amdgcn_mfma_f32_16x16x32_bf16(aF[m], bF[n], acc[m][n], 0, 0, 0);
    __builtin_amdgcn_s_setprio(0);
    // gate: tile i+1 landed (own 6 loads); tile i+2's 6 stay in flight.
    if (i < NT_K - 2)       { asm volatile("s_waitcnt vmcnt(6)" ::: "memory"); }
    else if (i == NT_K - 2) { asm volatile("s_waitcnt vmcnt(0)" ::: "memory"); }
    // ONE barrier per K-tile: every wave passed its lgkmcnt(0) (reads of the
    // buffer to be re-staged retired) and its vmcnt gate (next tile landed).
    __builtin_amdgcn_s_barrier();
    cur = (cur == 2) ? 0 : cur + 1;
    stg = (stg == 2) ? 0 : stg + 1;
  }

  // ---- epilogue: pair-merge (w adds w+4's partials), bias+relu, store ----
  __syncthreads();                          // staging LDS now dead; reuse
  float* mrg = (float*)sh;                  // 4 pairs x 32 KB = 128 KB
  if (kkw == 1) {
    float* base = mrg + wc*8192;
    #pragma unroll
    for (int m = 0; m < 8; ++m)
      #pragma unroll
      for (int n = 0; n < 4; ++n)
        *(f32x4*)(base + ((m*4 + n)*64 + lane)*4) = acc[m][n];
  }
  __syncthreads();
  if (kkw == 0) {
    float* base = mrg + wc*8192;
    #pragma unroll
    for (int m = 0; m < 8; ++m) {
      int gr = m0 + m*16 + lg*4;
      #pragma unroll
      for (int n = 0; n < 4; ++n) {
        f32x4 o = *(const f32x4*)(base + ((m*4 + n)*64 + lane)*4);
        int gc = n0 + wc*64 + n*16 + l15;
        float bv = bias[gc];
        #pragma unroll
        for (int i = 0; i < 4; ++i) {
          float v = acc[m][n][i] + o[i] + bv;
          C[(size_t)(gr + i)*ND + gc] = v > 0.f ? v : 0.f;
        }
      }
    }
  }
#undef STG_A
#undef STG_B
}

// ---------------------------------------------------------------------------
extern "C" void kernel_launch(void* const* d_in, const int* in_sizes, int n_in,
                              void* d_out, int out_size, void* d_ws, size_t ws_size,
                              hipStream_t stream) {
  (void)in_sizes; (void)n_in; (void)out_size; (void)ws_size;
  const float* x    = (const float*)d_in[0];   // [2048][4096]
  const float* c1   = (const float*)d_in[1];   // [16][16][32]
  const float* c2   = (const float*)d_in[2];   // [16][16][32][32]
  const float* c3   = (const float*)d_in[3];   // [16][16][32]
  const float* bias = (const float*)d_in[4];   // [4096]
  float* out = (float*)d_out;                  // [2048][4096]

  uint8_t* ws = (uint8_t*)d_ws;
  unsigned short* xb = (unsigned short*)(ws);              // 16 MB
  unsigned short* Wt = (unsigned short*)(ws + 16777216);   // 32 MB

  k_conv<<<4096, 256, 0, stream>>>(x, xb);
  k_wt  <<<256,  256, 0, stream>>>(c1, c2, c3, Wt);
  k_gemm<<<dim3(ND/256, MB/128), 512, 0, stream>>>(xb, Wt, bias, out);
}